// Round 1
// baseline (641.944 us; speedup 1.0000x reference)
//
#include <hip/hip_runtime.h>

#define BB 16
#define CC 384
#define HH 64
#define WWD 64
#define NH 8
#define HD 48
#define NW 1024
#define MTOK 65536
#define CPG 96
#define GSIZE (CPG*HH*WWD)   // 393216

typedef __attribute__((ext_vector_type(8))) short short8;
typedef __attribute__((ext_vector_type(4))) short shortx4;
typedef __attribute__((ext_vector_type(4))) float floatx4;

static __device__ __forceinline__ float b2f(short s) {
    return __uint_as_float(((unsigned int)(unsigned short)s) << 16);
}
static __device__ __forceinline__ unsigned short f2b(float f) {
    unsigned int u = __float_as_uint(f);
    u = (u + 0x7FFF + ((u >> 16) & 1)) >> 16;
    return (unsigned short)u;
}

// ---------------- GroupNorm stats ----------------
__global__ void gn_partial(const float* __restrict__ x, float* __restrict__ wsf) {
    int pair = blockIdx.x >> 3, slice = blockIdx.x & 7;
    const float4* p = (const float4*)(x + (size_t)pair * GSIZE + (size_t)slice * (GSIZE / 8));
    float s = 0.f, sq = 0.f;
    for (int i = threadIdx.x; i < GSIZE / 8 / 4; i += 256) {
        float4 v = p[i];
        s  += v.x + v.y + v.z + v.w;
        sq += v.x*v.x + v.y*v.y + v.z*v.z + v.w*v.w;
    }
    for (int o = 32; o; o >>= 1) { s += __shfl_down(s, o); sq += __shfl_down(sq, o); }
    __shared__ float ls[4], lq[4];
    int wv = threadIdx.x >> 6;
    if ((threadIdx.x & 63) == 0) { ls[wv] = s; lq[wv] = sq; }
    __syncthreads();
    if (threadIdx.x == 0) {
        s  = ls[0] + ls[1] + ls[2] + ls[3];
        sq = lq[0] + lq[1] + lq[2] + lq[3];
        wsf[pair * 8 + slice] = s;
        wsf[512 + pair * 8 + slice] = sq;
    }
}

__global__ void gn_final(float* wsf) {
    int p = threadIdx.x;  // 64 pairs
    float s = 0.f, sq = 0.f;
    for (int i = 0; i < 8; i++) { s += wsf[p * 8 + i]; sq += wsf[512 + p * 8 + i]; }
    float mean = s / (float)GSIZE;
    float var  = sq / (float)GSIZE - mean * mean;
    wsf[1024 + p] = mean;
    wsf[1088 + p] = rsqrtf(var + 1e-5f);
}

// ---------------- normalize + window-gather -> bf16 win[MTOK][384] ----------------
__global__ void norm_window(const float* __restrict__ x, const float* __restrict__ gamma,
                            const float* __restrict__ beta, const float* __restrict__ wsf,
                            unsigned short* __restrict__ win) {
    int nw = blockIdx.x;
    int b = nw >> 6, wh = (nw >> 3) & 7, ww = nw & 7;
    __shared__ float tile[CPG][66];
    int t = threadIdx.x;
    for (int g = 0; g < 4; g++) {
        float mean = wsf[1024 + b * 4 + g];
        float rstd = wsf[1088 + b * 4 + g];
        #pragma unroll
        for (int rr = 0; rr < 3; rr++) {
            int ridx = rr * 256 + t;          // 768 rows (cl,i)
            int cl = ridx >> 3, i = ridx & 7;
            int cg = g * CPG + cl;
            const float* src = x + (((size_t)b * CC + cg) * HH + wh * 8 + i) * WWD + ww * 8;
            float ga = gamma[cg], be = beta[cg];
            float4 v0 = *(const float4*)src;
            float4 v1 = *(const float4*)(src + 4);
            float* dst = &tile[cl][i * 8];
            dst[0] = (v0.x - mean) * rstd * ga + be;
            dst[1] = (v0.y - mean) * rstd * ga + be;
            dst[2] = (v0.z - mean) * rstd * ga + be;
            dst[3] = (v0.w - mean) * rstd * ga + be;
            dst[4] = (v1.x - mean) * rstd * ga + be;
            dst[5] = (v1.y - mean) * rstd * ga + be;
            dst[6] = (v1.z - mean) * rstd * ga + be;
            dst[7] = (v1.w - mean) * rstd * ga + be;
        }
        __syncthreads();
        #pragma unroll
        for (int it = 0; it < 24; it++) {
            int idx = it * 256 + t;           // 6144
            int cl = idx % 96, s = idx / 96;
            win[((size_t)nw * 64 + s) * CC + g * CPG + cl] = f2b(tile[cl][s]);
        }
        __syncthreads();
    }
}

// ---------------- weight convert (q rows prescaled) ----------------
__global__ void conv_w(const float* __restrict__ wqkv, const float* __restrict__ wproj,
                       unsigned short* __restrict__ wq_b, unsigned short* __restrict__ wp_b) {
    const int n1 = 1152 * 384, n2 = 384 * 384;
    const float qscale = 0.14433756729740643f;  // 1/sqrt(48)
    for (int i = blockIdx.x * 256 + threadIdx.x; i < n1 + n2; i += gridDim.x * 256) {
        if (i < n1) {
            float v = wqkv[i];
            if (i < 384 * 384) v *= qscale;      // q output rows
            wq_b[i] = f2b(v);
        } else {
            wp_b[i - n1] = f2b(wproj[i - n1]);
        }
    }
}

// ---------------- QKV GEMM: out[MTOK][1152] = win * wqkv^T (bf16 MFMA) ----------------
__launch_bounds__(256)
__global__ void gemm_qkv(const unsigned short* __restrict__ A, const unsigned short* __restrict__ Wb,
                         unsigned short* __restrict__ out) {
    const int K = 384, N = 1152;
    __shared__ unsigned short As[64][40], Bs[64][40];
    int m0 = blockIdx.y * 64, n0 = blockIdx.x * 64;
    int t = threadIdx.x;
    int lrow = t >> 2, lc8 = (t & 3) * 8;
    int lane = t & 63, wv = t >> 6;
    int wm = wv >> 1, wn = wv & 1;
    int quad = lane >> 4, l16 = lane & 15;
    floatx4 acc[2][2] = {};
    for (int k0 = 0; k0 < K; k0 += 32) {
        *(short8*)&As[lrow][lc8] = *(const short8*)&A[(size_t)(m0 + lrow) * K + k0 + lc8];
        *(short8*)&Bs[lrow][lc8] = *(const short8*)&Wb[(size_t)(n0 + lrow) * K + k0 + lc8];
        __syncthreads();
        short8 af[2], bf[2];
        af[0] = *(const short8*)&As[wm * 32 + l16][quad * 8];
        af[1] = *(const short8*)&As[wm * 32 + 16 + l16][quad * 8];
        bf[0] = *(const short8*)&Bs[wn * 32 + l16][quad * 8];
        bf[1] = *(const short8*)&Bs[wn * 32 + 16 + l16][quad * 8];
        #pragma unroll
        for (int mi = 0; mi < 2; mi++)
            #pragma unroll
            for (int ni = 0; ni < 2; ni++)
                acc[mi][ni] = __builtin_amdgcn_mfma_f32_16x16x32_bf16(af[mi], bf[ni], acc[mi][ni], 0, 0, 0);
        __syncthreads();
    }
    #pragma unroll
    for (int mi = 0; mi < 2; mi++)
        #pragma unroll
        for (int ni = 0; ni < 2; ni++) {
            int gm = m0 + wm * 32 + mi * 16 + quad * 4;
            int gn = n0 + wn * 32 + ni * 16 + l16;
            #pragma unroll
            for (int r = 0; r < 4; r++)
                out[(size_t)(gm + r) * N + gn] = f2b(acc[mi][ni][r]);
        }
}

// ---------------- attention per (window, head): fp32 vector ----------------
__launch_bounds__(256)
__global__ void attn(const unsigned short* __restrict__ qkv, unsigned short* __restrict__ hwin) {
    int wid = blockIdx.x >> 3, head = blockIdx.x & 7;
    __shared__ float qs[64][48], ks[64][48], vs[64][48];
    __shared__ float sc[64][65];
    int t = threadIdx.x;
    #pragma unroll
    for (int it = 0; it < 9; it++) {
        int idx = it * 256 + t;           // 2304 chunks of 4 elems
        int tensor = idx / 768, rem = idx % 768;
        int s = rem / 12, c4 = (rem % 12) * 4;
        const unsigned short* src = qkv + ((size_t)wid * 64 + s) * 1152 + tensor * 384 + head * 48 + c4;
        shortx4 v = *(const shortx4*)src;
        float* dst = (tensor == 0) ? &qs[s][c4] : (tensor == 1) ? &ks[s][c4] : &vs[s][c4];
        dst[0] = b2f(v.x); dst[1] = b2f(v.y); dst[2] = b2f(v.z); dst[3] = b2f(v.w);
    }
    __syncthreads();
    int r = t >> 2, seg = t & 3;
    float4 qv[12];
    #pragma unroll
    for (int c4 = 0; c4 < 12; c4++) qv[c4] = *(const float4*)&qs[r][c4 * 4];
    float rmax = -1e30f;
    float scv[16];
    #pragma unroll
    for (int nn = 0; nn < 16; nn++) {
        int n = seg + nn * 4;
        const float4* kp = (const float4*)&ks[n][0];
        float d = 0.f;
        #pragma unroll
        for (int c4 = 0; c4 < 12; c4++) {
            float4 kv = kp[c4];
            d += qv[c4].x * kv.x + qv[c4].y * kv.y + qv[c4].z * kv.z + qv[c4].w * kv.w;
        }
        scv[nn] = d;
        rmax = fmaxf(rmax, d);
    }
    rmax = fmaxf(rmax, __shfl_xor(rmax, 1));
    rmax = fmaxf(rmax, __shfl_xor(rmax, 2));
    float rsum = 0.f;
    #pragma unroll
    for (int nn = 0; nn < 16; nn++) {
        int n = seg + nn * 4;
        float p = __expf(scv[nn] - rmax);
        sc[r][n] = p;
        rsum += p;
    }
    rsum += __shfl_xor(rsum, 1);
    rsum += __shfl_xor(rsum, 2);
    float inv = 1.f / rsum;
    float acc[12] = {};
    for (int n = 0; n < 64; n++) {
        float p = sc[r][n];
        const float* vp = &vs[n][seg * 12];
        #pragma unroll
        for (int c = 0; c < 12; c++) acc[c] += p * vp[c];
    }
    unsigned short* dst = hwin + ((size_t)wid * 64 + r) * 384 + head * 48 + seg * 12;
    #pragma unroll
    for (int c = 0; c < 12; c++) dst[c] = f2b(acc[c] * inv);
}

// ---------------- proj GEMM + bias + residual -> out (B,C,H,W) fp32 ----------------
__launch_bounds__(256)
__global__ void gemm_proj(const unsigned short* __restrict__ A, const unsigned short* __restrict__ Wb,
                          const float* __restrict__ bias, const float* __restrict__ x,
                          float* __restrict__ out) {
    const int K = 384;
    __shared__ unsigned short As[64][40], Bs[64][40];
    int m0 = blockIdx.y * 64, n0 = blockIdx.x * 64;
    int t = threadIdx.x;
    int lrow = t >> 2, lc8 = (t & 3) * 8;
    int lane = t & 63, wv = t >> 6;
    int wm = wv >> 1, wn = wv & 1;
    int quad = lane >> 4, l16 = lane & 15;
    floatx4 acc[2][2] = {};
    for (int k0 = 0; k0 < K; k0 += 32) {
        *(short8*)&As[lrow][lc8] = *(const short8*)&A[(size_t)(m0 + lrow) * K + k0 + lc8];
        *(short8*)&Bs[lrow][lc8] = *(const short8*)&Wb[(size_t)(n0 + lrow) * K + k0 + lc8];
        __syncthreads();
        short8 af[2], bf[2];
        af[0] = *(const short8*)&As[wm * 32 + l16][quad * 8];
        af[1] = *(const short8*)&As[wm * 32 + 16 + l16][quad * 8];
        bf[0] = *(const short8*)&Bs[wn * 32 + l16][quad * 8];
        bf[1] = *(const short8*)&Bs[wn * 32 + 16 + l16][quad * 8];
        #pragma unroll
        for (int mi = 0; mi < 2; mi++)
            #pragma unroll
            for (int ni = 0; ni < 2; ni++)
                acc[mi][ni] = __builtin_amdgcn_mfma_f32_16x16x32_bf16(af[mi], bf[ni], acc[mi][ni], 0, 0, 0);
        __syncthreads();
    }
    #pragma unroll
    for (int mi = 0; mi < 2; mi++)
        #pragma unroll
        for (int ni = 0; ni < 2; ni++) {
            int gm = m0 + wm * 32 + mi * 16 + quad * 4;   // token base, 4 consecutive tokens
            int gn = n0 + wn * 32 + ni * 16 + l16;        // channel
            float bv = bias[gn];
            int nw = gm >> 6, s = gm & 63;
            int b = nw >> 6, wh = (nw >> 3) & 7, ww = nw & 7;
            int i = s >> 3, jb = s & 7;                   // jb in {0,4}
            size_t o = (((size_t)b * CC + gn) * HH + wh * 8 + i) * WWD + ww * 8 + jb;
            float4 xv = *(const float4*)(x + o);
            float4 ov;
            ov.x = acc[mi][ni][0] + bv + xv.x;
            ov.y = acc[mi][ni][1] + bv + xv.y;
            ov.z = acc[mi][ni][2] + bv + xv.z;
            ov.w = acc[mi][ni][3] + bv + xv.w;
            *(float4*)(out + o) = ov;
        }
}

// ---------------- launch ----------------
extern "C" void kernel_launch(void* const* d_in, const int* in_sizes, int n_in,
                              void* d_out, int out_size, void* d_ws, size_t ws_size,
                              hipStream_t stream) {
    const float* x     = (const float*)d_in[0];
    const float* gnw   = (const float*)d_in[1];
    const float* gnb   = (const float*)d_in[2];
    const float* wqkv  = (const float*)d_in[3];
    const float* wproj = (const float*)d_in[4];
    const float* bproj = (const float*)d_in[5];
    float* out = (float*)d_out;

    char* ws = (char*)d_ws;
    float* wsf = (float*)ws;
    const size_t OFF_WQ  = 8192;
    const size_t OFF_WP  = OFF_WQ + (size_t)1152 * 384 * 2;          // 892928
    const size_t OFF_WIN = 2097152;
    const size_t OFF_QKV = OFF_WIN + (size_t)MTOK * CC * 2 + 2048;   // after win
    unsigned short* wq_b = (unsigned short*)(ws + OFF_WQ);
    unsigned short* wp_b = (unsigned short*)(ws + OFF_WP);
    unsigned short* win  = (unsigned short*)(ws + OFF_WIN);
    unsigned short* qkvb = (unsigned short*)(ws + OFF_QKV);
    unsigned short* hwin = win;   // win is dead after gemm_qkv; reuse for attention output

    gn_partial<<<512, 256, 0, stream>>>(x, wsf);
    conv_w<<<2304, 256, 0, stream>>>(wqkv, wproj, wq_b, wp_b);
    gn_final<<<1, 64, 0, stream>>>(wsf);
    norm_window<<<1024, 256, 0, stream>>>(x, gnw, gnb, wsf, win);
    dim3 g1(18, 1024);
    gemm_qkv<<<g1, 256, 0, stream>>>(win, wq_b, qkvb);
    attn<<<8192, 256, 0, stream>>>(qkvb, hwin);
    dim3 g2(6, 1024);
    gemm_proj<<<g2, 256, 0, stream>>>(hwin, wp_b, bproj, x, out);
}

// Round 2
// 504.145 us; speedup vs baseline: 1.2733x; 1.2733x over previous
//
#include <hip/hip_runtime.h>

#define BB 16
#define CC 384
#define HH 64
#define WWD 64
#define NH 8
#define HD 48
#define NW 1024
#define MTOK 65536
#define CPG 96
#define GSIZE (CPG*HH*WWD)   // 393216

typedef __attribute__((ext_vector_type(8))) short short8;
typedef __attribute__((ext_vector_type(4))) short shortx4;
typedef __attribute__((ext_vector_type(4))) float floatx4;

static __device__ __forceinline__ float b2f(short s) {
    return __uint_as_float(((unsigned int)(unsigned short)s) << 16);
}
static __device__ __forceinline__ unsigned short f2b(float f) {
    unsigned int u = __float_as_uint(f);
    u = (u + 0x7FFF + ((u >> 16) & 1)) >> 16;
    return (unsigned short)u;
}

// async 16B/lane global->LDS. LDS dest must be wave-uniform base; HW scatters lane*16.
typedef __attribute__((address_space(1))) void gvoid;
typedef __attribute__((address_space(3))) void lvoid;
static __device__ __forceinline__ void gld16(const unsigned short* g, unsigned short* l) {
    __builtin_amdgcn_global_load_lds((gvoid*)(unsigned long long)g,
                                     (lvoid*)(unsigned int)(unsigned long long)l,
                                     16, 0, 0);
}

// ---------------- GroupNorm stats ----------------
__global__ void gn_partial(const float* __restrict__ x, float* __restrict__ wsf) {
    int pair = blockIdx.x >> 3, slice = blockIdx.x & 7;
    const float4* p = (const float4*)(x + (size_t)pair * GSIZE + (size_t)slice * (GSIZE / 8));
    float s = 0.f, sq = 0.f;
    for (int i = threadIdx.x; i < GSIZE / 8 / 4; i += 256) {
        float4 v = p[i];
        s  += v.x + v.y + v.z + v.w;
        sq += v.x*v.x + v.y*v.y + v.z*v.z + v.w*v.w;
    }
    for (int o = 32; o; o >>= 1) { s += __shfl_down(s, o); sq += __shfl_down(sq, o); }
    __shared__ float ls[4], lq[4];
    int wv = threadIdx.x >> 6;
    if ((threadIdx.x & 63) == 0) { ls[wv] = s; lq[wv] = sq; }
    __syncthreads();
    if (threadIdx.x == 0) {
        s  = ls[0] + ls[1] + ls[2] + ls[3];
        sq = lq[0] + lq[1] + lq[2] + lq[3];
        wsf[pair * 8 + slice] = s;
        wsf[512 + pair * 8 + slice] = sq;
    }
}

__global__ void gn_final(float* wsf) {
    int p = threadIdx.x;  // 64 (batch,group) pairs
    float s = 0.f, sq = 0.f;
    for (int i = 0; i < 8; i++) { s += wsf[p * 8 + i]; sq += wsf[512 + p * 8 + i]; }
    float mean = s / (float)GSIZE;
    float var  = sq / (float)GSIZE - mean * mean;
    wsf[1024 + p] = mean;
    wsf[1088 + p] = rsqrtf(var + 1e-5f);
}

// ---------------- normalize + window-gather -> bf16 win[MTOK][384] ----------------
__global__ void norm_window(const float* __restrict__ x, const float* __restrict__ gamma,
                            const float* __restrict__ beta, const float* __restrict__ wsf,
                            unsigned short* __restrict__ win) {
    int nw = blockIdx.x;
    int b = nw >> 6, wh = (nw >> 3) & 7, ww = nw & 7;
    __shared__ float tile[CPG][66];
    int t = threadIdx.x;
    for (int g = 0; g < 4; g++) {
        float mean = wsf[1024 + b * 4 + g];
        float rstd = wsf[1088 + b * 4 + g];
        #pragma unroll
        for (int rr = 0; rr < 3; rr++) {
            int ridx = rr * 256 + t;
            int cl = ridx >> 3, i = ridx & 7;
            int cg = g * CPG + cl;
            const float* src = x + (((size_t)b * CC + cg) * HH + wh * 8 + i) * WWD + ww * 8;
            float ga = gamma[cg], be = beta[cg];
            float4 v0 = *(const float4*)src;
            float4 v1 = *(const float4*)(src + 4);
            float* dst = &tile[cl][i * 8];
            dst[0] = (v0.x - mean) * rstd * ga + be;
            dst[1] = (v0.y - mean) * rstd * ga + be;
            dst[2] = (v0.z - mean) * rstd * ga + be;
            dst[3] = (v0.w - mean) * rstd * ga + be;
            dst[4] = (v1.x - mean) * rstd * ga + be;
            dst[5] = (v1.y - mean) * rstd * ga + be;
            dst[6] = (v1.z - mean) * rstd * ga + be;
            dst[7] = (v1.w - mean) * rstd * ga + be;
        }
        __syncthreads();
        #pragma unroll
        for (int it = 0; it < 24; it++) {
            int idx = it * 256 + t;
            int cl = idx % 96, s = idx / 96;
            win[((size_t)nw * 64 + s) * CC + g * CPG + cl] = f2b(tile[cl][s]);
        }
        __syncthreads();
    }
}

// ---------------- weight convert (q rows prescaled) ----------------
__global__ void conv_w(const float* __restrict__ wqkv, const float* __restrict__ wproj,
                       unsigned short* __restrict__ wq_b, unsigned short* __restrict__ wp_b) {
    const int n1 = 1152 * 384, n2 = 384 * 384;
    const float qscale = 0.14433756729740643f;  // 1/sqrt(48)
    for (int i = blockIdx.x * 256 + threadIdx.x; i < n1 + n2; i += gridDim.x * 256) {
        if (i < n1) {
            float v = wqkv[i];
            if (i < 384 * 384) v *= qscale;
            wq_b[i] = f2b(v);
        } else {
            wp_b[i - n1] = f2b(wproj[i - n1]);
        }
    }
}

// ---------------- 128x128 bf16 MFMA GEMM: out = A(M,384) * W(N,384)^T -> bf16 ----------------
__launch_bounds__(256)
__global__ void gemm_qkv(const unsigned short* __restrict__ A, const unsigned short* __restrict__ Wb,
                         unsigned short* __restrict__ out) {
    const int K = 384, N = 1152;
    __shared__ unsigned short As[128 * 32], Bs[128 * 32];   // unpadded: global_load_lds layout
    int m0 = blockIdx.y * 128, n0 = blockIdx.x * 128;
    int t = threadIdx.x;
    int lane = t & 63, wv = t >> 6;
    int wm = wv >> 1, wn = wv & 1;
    int quad = lane >> 4, l16 = lane & 15;
    int sr = lane >> 2, sc = (lane & 3) * 8;
    floatx4 acc[4][4] = {};
    for (int k0 = 0; k0 < K; k0 += 32) {
        const unsigned short* ga = A  + (size_t)(m0 + wv * 32 + sr) * K + k0 + sc;
        const unsigned short* gb = Wb + (size_t)(n0 + wv * 32 + sr) * K + k0 + sc;
        gld16(ga,            &As[wv * 1024]);
        gld16(ga + 16 * K,   &As[wv * 1024 + 512]);
        gld16(gb,            &Bs[wv * 1024]);
        gld16(gb + 16 * K,   &Bs[wv * 1024 + 512]);
        __syncthreads();
        short8 af[4], bf[4];
        #pragma unroll
        for (int mi = 0; mi < 4; mi++)
            af[mi] = *(const short8*)&As[(wm * 64 + mi * 16 + l16) * 32 + quad * 8];
        #pragma unroll
        for (int ni = 0; ni < 4; ni++)
            bf[ni] = *(const short8*)&Bs[(wn * 64 + ni * 16 + l16) * 32 + quad * 8];
        #pragma unroll
        for (int mi = 0; mi < 4; mi++)
            #pragma unroll
            for (int ni = 0; ni < 4; ni++)
                acc[mi][ni] = __builtin_amdgcn_mfma_f32_16x16x32_bf16(af[mi], bf[ni], acc[mi][ni], 0, 0, 0);
        __syncthreads();
    }
    #pragma unroll
    for (int mi = 0; mi < 4; mi++)
        #pragma unroll
        for (int ni = 0; ni < 4; ni++) {
            int gm = m0 + wm * 64 + mi * 16 + quad * 4;
            int gn = n0 + wn * 64 + ni * 16 + l16;
            #pragma unroll
            for (int r = 0; r < 4; r++)
                out[(size_t)(gm + r) * N + gn] = f2b(acc[mi][ni][r]);
        }
}

// ---------------- MFMA attention: one wave per (window, head) ----------------
__launch_bounds__(256)
__global__ void attn(const unsigned short* __restrict__ qkv, unsigned short* __restrict__ hwin) {
    __shared__ unsigned short Pl[4][64 * 72];   // per-wave P (stride 72: 16B-aligned, <=2-way banks)
    __shared__ unsigned short Vt[4][48 * 72];   // per-wave V^T
    int t = threadIdx.x;
    int wv = t >> 6, lane = t & 63;
    int gw = blockIdx.x * 4 + wv;
    int wid = gw >> 3, head = gw & 7;
    int quad = lane >> 4, l16 = lane & 15;
    const unsigned short* base = qkv + (size_t)wid * 64 * 1152 + head * 48;

    // stage V transposed: lane = s row; Vt[d][s]
    {
        const unsigned short* vrow = base + 768 + (size_t)lane * 1152;
        #pragma unroll
        for (int c4 = 0; c4 < 12; c4++) {
            shortx4 v = *(const shortx4*)(vrow + c4 * 4);
            Vt[wv][(c4 * 4 + 0) * 72 + lane] = (unsigned short)v.x;
            Vt[wv][(c4 * 4 + 1) * 72 + lane] = (unsigned short)v.y;
            Vt[wv][(c4 * 4 + 2) * 72 + lane] = (unsigned short)v.z;
            Vt[wv][(c4 * 4 + 3) * 72 + lane] = (unsigned short)v.w;
        }
    }

    // S = Q*K^T (scale pre-folded into Wq). K=48 -> kstep 0 full, kstep 1 masked.
    floatx4 acc[4][4] = {};
    #pragma unroll
    for (int ks = 0; ks < 2; ks++) {
        short8 qf[4], kf[4];
        #pragma unroll
        for (int mi = 0; mi < 4; mi++)
            qf[mi] = *(const short8*)(base + (size_t)(mi * 16 + l16) * 1152 + ks * 32 + quad * 8);
        #pragma unroll
        for (int ni = 0; ni < 4; ni++) {
            if (ks == 1 && quad >= 2) kf[ni] = (short8){};   // zero B kills k=48..63 products
            else kf[ni] = *(const short8*)(base + 384 + (size_t)(ni * 16 + l16) * 1152 + ks * 32 + quad * 8);
        }
        #pragma unroll
        for (int mi = 0; mi < 4; mi++)
            #pragma unroll
            for (int ni = 0; ni < 4; ni++)
                acc[mi][ni] = __builtin_amdgcn_mfma_f32_16x16x32_bf16(qf[mi], kf[ni], acc[mi][ni], 0, 0, 0);
    }

    // softmax in C-layout: lane owns rows (mi*16 + quad*4 + r), cols (ni*16 + l16)
    float mx[4][4], sm[4][4];
    #pragma unroll
    for (int mi = 0; mi < 4; mi++)
        #pragma unroll
        for (int r = 0; r < 4; r++) {
            float m = acc[mi][0][r];
            m = fmaxf(m, acc[mi][1][r]);
            m = fmaxf(m, acc[mi][2][r]);
            m = fmaxf(m, acc[mi][3][r]);
            mx[mi][r] = m;
        }
    #pragma unroll
    for (int mask = 1; mask < 16; mask <<= 1)
        #pragma unroll
        for (int mi = 0; mi < 4; mi++)
            #pragma unroll
            for (int r = 0; r < 4; r++)
                mx[mi][r] = fmaxf(mx[mi][r], __shfl_xor(mx[mi][r], mask));
    #pragma unroll
    for (int mi = 0; mi < 4; mi++)
        #pragma unroll
        for (int r = 0; r < 4; r++) {
            float s = 0.f;
            #pragma unroll
            for (int ni = 0; ni < 4; ni++) {
                float p = __expf(acc[mi][ni][r] - mx[mi][r]);
                acc[mi][ni][r] = p;
                s += p;
            }
            sm[mi][r] = s;
        }
    #pragma unroll
    for (int mask = 1; mask < 16; mask <<= 1)
        #pragma unroll
        for (int mi = 0; mi < 4; mi++)
            #pragma unroll
            for (int r = 0; r < 4; r++)
                sm[mi][r] += __shfl_xor(sm[mi][r], mask);

    // write P (pre-scaled by 1/rowsum) to LDS for C->A layout transform
    #pragma unroll
    for (int mi = 0; mi < 4; mi++)
        #pragma unroll
        for (int r = 0; r < 4; r++) {
            float inv = 1.f / sm[mi][r];
            int row = mi * 16 + quad * 4 + r;
            #pragma unroll
            for (int ni = 0; ni < 4; ni++)
                Pl[wv][row * 72 + ni * 16 + l16] = f2b(acc[mi][ni][r] * inv);
        }

    // O = P(64x64) * Vt^T -> (64 x 48)
    floatx4 o[4][3] = {};
    #pragma unroll
    for (int ks = 0; ks < 2; ks++) {
        short8 pf[4], vf[3];
        #pragma unroll
        for (int mi = 0; mi < 4; mi++)
            pf[mi] = *(const short8*)&Pl[wv][(mi * 16 + l16) * 72 + ks * 32 + quad * 8];
        #pragma unroll
        for (int ni = 0; ni < 3; ni++)
            vf[ni] = *(const short8*)&Vt[wv][(ni * 16 + l16) * 72 + ks * 32 + quad * 8];
        #pragma unroll
        for (int mi = 0; mi < 4; mi++)
            #pragma unroll
            for (int ni = 0; ni < 3; ni++)
                o[mi][ni] = __builtin_amdgcn_mfma_f32_16x16x32_bf16(pf[mi], vf[ni], o[mi][ni], 0, 0, 0);
    }

    unsigned short* orow = hwin + (size_t)wid * 64 * 384 + head * 48;
    #pragma unroll
    for (int mi = 0; mi < 4; mi++)
        #pragma unroll
        for (int ni = 0; ni < 3; ni++)
            #pragma unroll
            for (int r = 0; r < 4; r++)
                orow[(size_t)(mi * 16 + quad * 4 + r) * 384 + ni * 16 + l16] = f2b(o[mi][ni][r]);
}

// ---------------- 128x128 proj GEMM + bias + residual -> out (B,C,H,W) fp32 ----------------
__launch_bounds__(256)
__global__ void gemm_proj(const unsigned short* __restrict__ A, const unsigned short* __restrict__ Wb,
                          const float* __restrict__ bias, const float* __restrict__ x,
                          float* __restrict__ out) {
    const int K = 384;
    __shared__ unsigned short As[128 * 32], Bs[128 * 32];
    int m0 = blockIdx.y * 128, n0 = blockIdx.x * 128;
    int t = threadIdx.x;
    int lane = t & 63, wv = t >> 6;
    int wm = wv >> 1, wn = wv & 1;
    int quad = lane >> 4, l16 = lane & 15;
    int sr = lane >> 2, sc = (lane & 3) * 8;
    floatx4 acc[4][4] = {};
    for (int k0 = 0; k0 < K; k0 += 32) {
        const unsigned short* ga = A  + (size_t)(m0 + wv * 32 + sr) * K + k0 + sc;
        const unsigned short* gb = Wb + (size_t)(n0 + wv * 32 + sr) * K + k0 + sc;
        gld16(ga,          &As[wv * 1024]);
        gld16(ga + 16 * K, &As[wv * 1024 + 512]);
        gld16(gb,          &Bs[wv * 1024]);
        gld16(gb + 16 * K, &Bs[wv * 1024 + 512]);
        __syncthreads();
        short8 af[4], bf[4];
        #pragma unroll
        for (int mi = 0; mi < 4; mi++)
            af[mi] = *(const short8*)&As[(wm * 64 + mi * 16 + l16) * 32 + quad * 8];
        #pragma unroll
        for (int ni = 0; ni < 4; ni++)
            bf[ni] = *(const short8*)&Bs[(wn * 64 + ni * 16 + l16) * 32 + quad * 8];
        #pragma unroll
        for (int mi = 0; mi < 4; mi++)
            #pragma unroll
            for (int ni = 0; ni < 4; ni++)
                acc[mi][ni] = __builtin_amdgcn_mfma_f32_16x16x32_bf16(af[mi], bf[ni], acc[mi][ni], 0, 0, 0);
        __syncthreads();
    }
    #pragma unroll
    for (int mi = 0; mi < 4; mi++)
        #pragma unroll
        for (int ni = 0; ni < 4; ni++) {
            int gm = m0 + wm * 64 + mi * 16 + quad * 4;   // 4 consecutive tokens = 4 w-pixels
            int gn = n0 + wn * 64 + ni * 16 + l16;        // channel
            float bv = bias[gn];
            int nw = gm >> 6, s = gm & 63;
            int b = nw >> 6, wh = (nw >> 3) & 7, ww = nw & 7;
            int i = s >> 3, jb = s & 7;                   // jb in {0,4}
            size_t o = (((size_t)b * CC + gn) * HH + wh * 8 + i) * WWD + ww * 8 + jb;
            float4 xv = *(const float4*)(x + o);
            float4 ov;
            ov.x = acc[mi][ni][0] + bv + xv.x;
            ov.y = acc[mi][ni][1] + bv + xv.y;
            ov.z = acc[mi][ni][2] + bv + xv.z;
            ov.w = acc[mi][ni][3] + bv + xv.w;
            *(float4*)(out + o) = ov;
        }
}

// ---------------- launch ----------------
extern "C" void kernel_launch(void* const* d_in, const int* in_sizes, int n_in,
                              void* d_out, int out_size, void* d_ws, size_t ws_size,
                              hipStream_t stream) {
    const float* x     = (const float*)d_in[0];
    const float* gnw   = (const float*)d_in[1];
    const float* gnb   = (const float*)d_in[2];
    const float* wqkv  = (const float*)d_in[3];
    const float* wproj = (const float*)d_in[4];
    const float* bproj = (const float*)d_in[5];
    float* out = (float*)d_out;

    char* ws = (char*)d_ws;
    float* wsf = (float*)ws;
    const size_t OFF_WQ  = 8192;
    const size_t OFF_WP  = OFF_WQ + (size_t)1152 * 384 * 2;
    const size_t OFF_WIN = 2097152;
    const size_t OFF_QKV = OFF_WIN + (size_t)MTOK * CC * 2 + 2048;
    unsigned short* wq_b = (unsigned short*)(ws + OFF_WQ);
    unsigned short* wp_b = (unsigned short*)(ws + OFF_WP);
    unsigned short* win  = (unsigned short*)(ws + OFF_WIN);
    unsigned short* qkvb = (unsigned short*)(ws + OFF_QKV);
    unsigned short* hwin = win;   // win dead after gemm_qkv; reuse for attention output

    gn_partial<<<512, 256, 0, stream>>>(x, wsf);
    conv_w<<<2304, 256, 0, stream>>>(wqkv, wproj, wq_b, wp_b);
    gn_final<<<1, 64, 0, stream>>>(wsf);
    norm_window<<<1024, 256, 0, stream>>>(x, gnw, gnb, wsf, win);
    dim3 g1(9, 512);
    gemm_qkv<<<g1, 256, 0, stream>>>(win, wq_b, qkvb);
    attn<<<2048, 256, 0, stream>>>(qkvb, hwin);
    dim3 g2(3, 512);
    gemm_proj<<<g2, 256, 0, stream>>>(hwin, wp_b, bproj, x, out);
}

// Round 3
// 488.876 us; speedup vs baseline: 1.3131x; 1.0312x over previous
//
#include <hip/hip_runtime.h>

#define BB 16
#define CC 384
#define HH 64
#define WWD 64
#define NH 8
#define HD 48
#define NW 1024
#define MTOK 65536
#define CPG 96
#define GSIZE (CPG*HH*WWD)   // 393216

typedef __attribute__((ext_vector_type(8))) short short8;
typedef __attribute__((ext_vector_type(4))) short shortx4;
typedef __attribute__((ext_vector_type(4))) float floatx4;

static __device__ __forceinline__ float b2f(short s) {
    return __uint_as_float(((unsigned int)(unsigned short)s) << 16);
}
static __device__ __forceinline__ unsigned short f2b(float f) {
    unsigned int u = __float_as_uint(f);
    u = (u + 0x7FFF + ((u >> 16) & 1)) >> 16;
    return (unsigned short)u;
}

// async 16B/lane global->LDS. LDS dest is wave-uniform base; HW scatters lane*16.
typedef __attribute__((address_space(1))) void gvoid;
typedef __attribute__((address_space(3))) void lvoid;
static __device__ __forceinline__ void gld16(const unsigned short* g, unsigned short* l) {
    __builtin_amdgcn_global_load_lds((gvoid*)(unsigned long long)g,
                                     (lvoid*)(unsigned int)(unsigned long long)l,
                                     16, 0, 0);
}

// ---------------- GroupNorm stats ----------------
__global__ void gn_partial(const float* __restrict__ x, float* __restrict__ wsf) {
    int pair = blockIdx.x >> 3, slice = blockIdx.x & 7;
    const float4* p = (const float4*)(x + (size_t)pair * GSIZE + (size_t)slice * (GSIZE / 8));
    float s = 0.f, sq = 0.f;
    for (int i = threadIdx.x; i < GSIZE / 8 / 4; i += 256) {
        float4 v = p[i];
        s  += v.x + v.y + v.z + v.w;
        sq += v.x*v.x + v.y*v.y + v.z*v.z + v.w*v.w;
    }
    for (int o = 32; o; o >>= 1) { s += __shfl_down(s, o); sq += __shfl_down(sq, o); }
    __shared__ float ls[4], lq[4];
    int wv = threadIdx.x >> 6;
    if ((threadIdx.x & 63) == 0) { ls[wv] = s; lq[wv] = sq; }
    __syncthreads();
    if (threadIdx.x == 0) {
        s  = ls[0] + ls[1] + ls[2] + ls[3];
        sq = lq[0] + lq[1] + lq[2] + lq[3];
        wsf[pair * 8 + slice] = s;
        wsf[512 + pair * 8 + slice] = sq;
    }
}

__global__ void gn_final(float* wsf) {
    int p = threadIdx.x;  // 64 (batch,group) pairs
    float s = 0.f, sq = 0.f;
    for (int i = 0; i < 8; i++) { s += wsf[p * 8 + i]; sq += wsf[512 + p * 8 + i]; }
    float mean = s / (float)GSIZE;
    float var  = sq / (float)GSIZE - mean * mean;
    wsf[1024 + p] = mean;
    wsf[1088 + p] = rsqrtf(var + 1e-5f);
}

// ---------------- normalize + window-gather -> bf16 win[MTOK][384] ----------------
__global__ void norm_window(const float* __restrict__ x, const float* __restrict__ gamma,
                            const float* __restrict__ beta, const float* __restrict__ wsf,
                            unsigned short* __restrict__ win) {
    int nw = blockIdx.x;
    int b = nw >> 6, wh = (nw >> 3) & 7, ww = nw & 7;
    __shared__ float tile[CPG][66];
    int t = threadIdx.x;
    for (int g = 0; g < 4; g++) {
        float mean = wsf[1024 + b * 4 + g];
        float rstd = wsf[1088 + b * 4 + g];
        #pragma unroll
        for (int rr = 0; rr < 3; rr++) {
            int ridx = rr * 256 + t;
            int cl = ridx >> 3, i = ridx & 7;
            int cg = g * CPG + cl;
            const float* src = x + (((size_t)b * CC + cg) * HH + wh * 8 + i) * WWD + ww * 8;
            float ga = gamma[cg], be = beta[cg];
            float4 v0 = *(const float4*)src;
            float4 v1 = *(const float4*)(src + 4);
            float* dst = &tile[cl][i * 8];
            dst[0] = (v0.x - mean) * rstd * ga + be;
            dst[1] = (v0.y - mean) * rstd * ga + be;
            dst[2] = (v0.z - mean) * rstd * ga + be;
            dst[3] = (v0.w - mean) * rstd * ga + be;
            dst[4] = (v1.x - mean) * rstd * ga + be;
            dst[5] = (v1.y - mean) * rstd * ga + be;
            dst[6] = (v1.z - mean) * rstd * ga + be;
            dst[7] = (v1.w - mean) * rstd * ga + be;
        }
        __syncthreads();
        #pragma unroll
        for (int it = 0; it < 24; it++) {
            int idx = it * 256 + t;
            int cl = idx % 96, s = idx / 96;
            win[((size_t)nw * 64 + s) * CC + g * CPG + cl] = f2b(tile[cl][s]);
        }
        __syncthreads();
    }
}

// ---------------- weight convert (q rows prescaled) ----------------
__global__ void conv_w(const float* __restrict__ wqkv, const float* __restrict__ wproj,
                       unsigned short* __restrict__ wq_b, unsigned short* __restrict__ wp_b) {
    const int n1 = 1152 * 384, n2 = 384 * 384;
    const float qscale = 0.14433756729740643f;  // 1/sqrt(48)
    for (int i = blockIdx.x * 256 + threadIdx.x; i < n1 + n2; i += gridDim.x * 256) {
        if (i < n1) {
            float v = wqkv[i];
            if (i < 384 * 384) v *= qscale;
            wq_b[i] = f2b(v);
        } else {
            wp_b[i - n1] = f2b(wproj[i - n1]);
        }
    }
}

// ---------------- 128x128 bf16 MFMA GEMM (BK=64, XCD swizzle, LDS epilogue) ----------------
__launch_bounds__(256)
__global__ void gemm_qkv(const unsigned short* __restrict__ A, const unsigned short* __restrict__ Wb,
                         unsigned short* __restrict__ out) {
    const int K = 384, N = 1152;
    // staging: As = smem[0..8192), Bs = smem[8192..16384), each 2 panels x 128x32
    // epilogue: 128 rows x stride 136 shorts (16B-aligned rows)
    __shared__ __align__(16) unsigned short smem[128 * 136];
    unsigned short* As = smem;
    unsigned short* Bs = smem + 8192;
    int l = blockIdx.x;
    int xcd = l & 7, li = l >> 3;                  // XCD x gets contiguous m-band, n fastest
    int m0 = (xcd * 64 + li / 9) * 128, n0 = (li % 9) * 128;
    int t = threadIdx.x;
    int lane = t & 63, wv = t >> 6;
    int wm = wv >> 1, wn = wv & 1;
    int quad = lane >> 4, l16 = lane & 15;
    int sr = lane >> 2, sc = (lane & 3) * 8;       // 16 rows x 32 shorts per gld16
    floatx4 acc[4][4] = {};
    for (int k0 = 0; k0 < K; k0 += 64) {
        #pragma unroll
        for (int p = 0; p < 2; p++)
            #pragma unroll
            for (int rh = 0; rh < 2; rh++) {
                const unsigned short* ga = A  + (size_t)(m0 + wv * 32 + rh * 16 + sr) * K + k0 + p * 32 + sc;
                const unsigned short* gb = Wb + (size_t)(n0 + wv * 32 + rh * 16 + sr) * K + k0 + p * 32 + sc;
                gld16(ga, &As[p * 4096 + (wv * 32 + rh * 16) * 32]);
                gld16(gb, &Bs[p * 4096 + (wv * 32 + rh * 16) * 32]);
            }
        __syncthreads();
        #pragma unroll
        for (int p = 0; p < 2; p++) {
            short8 af[4], bf[4];
            #pragma unroll
            for (int mi = 0; mi < 4; mi++)
                af[mi] = *(const short8*)&As[p * 4096 + (wm * 64 + mi * 16 + l16) * 32 + quad * 8];
            #pragma unroll
            for (int ni = 0; ni < 4; ni++)
                bf[ni] = *(const short8*)&Bs[p * 4096 + (wn * 64 + ni * 16 + l16) * 32 + quad * 8];
            #pragma unroll
            for (int mi = 0; mi < 4; mi++)
                #pragma unroll
                for (int ni = 0; ni < 4; ni++)
                    acc[mi][ni] = __builtin_amdgcn_mfma_f32_16x16x32_bf16(af[mi], bf[ni], acc[mi][ni], 0, 0, 0);
        }
        __syncthreads();
    }
    // epilogue: acc (C-layout) -> LDS -> coalesced short8 stores
    #pragma unroll
    for (int mi = 0; mi < 4; mi++)
        #pragma unroll
        for (int ni = 0; ni < 4; ni++) {
            int row = wm * 64 + mi * 16 + quad * 4;
            int col = wn * 64 + ni * 16 + l16;
            #pragma unroll
            for (int r = 0; r < 4; r++)
                smem[(row + r) * 136 + col] = f2b(acc[mi][ni][r]);
        }
    __syncthreads();
    int srow = wv * 4 + quad;
    #pragma unroll
    for (int i2 = 0; i2 < 8; i2++) {
        int row = srow + i2 * 16;
        short8 vv = *(const short8*)&smem[row * 136 + l16 * 8];
        *(short8*)&out[(size_t)(m0 + row) * N + n0 + l16 * 8] = vv;
    }
}

// ---------------- MFMA attention: one wave per (window, head) ----------------
__launch_bounds__(256)
__global__ void attn(const unsigned short* __restrict__ qkv, unsigned short* __restrict__ hwin) {
    __shared__ unsigned short Pl[4][64 * 72];   // per-wave P / O-staging
    __shared__ unsigned short Vt[4][48 * 72];   // per-wave V^T
    int t = threadIdx.x;
    int wv = t >> 6, lane = t & 63;
    int gw = blockIdx.x * 4 + wv;
    int wid = gw >> 3, head = gw & 7;
    int quad = lane >> 4, l16 = lane & 15;
    const unsigned short* base = qkv + (size_t)wid * 64 * 1152 + head * 48;

    // stage V transposed: lane = s row; Vt[d][s]
    {
        const unsigned short* vrow = base + 768 + (size_t)lane * 1152;
        #pragma unroll
        for (int c8 = 0; c8 < 6; c8++) {
            short8 v = *(const short8*)(vrow + c8 * 8);
            #pragma unroll
            for (int j = 0; j < 8; j++)
                Vt[wv][(c8 * 8 + j) * 72 + lane] = (unsigned short)v[j];
        }
    }

    // S = Q*K^T (scale pre-folded into Wq). K=48 -> kstep 0 full, kstep 1 masked.
    floatx4 acc[4][4] = {};
    #pragma unroll
    for (int ks = 0; ks < 2; ks++) {
        short8 qf[4], kf[4];
        #pragma unroll
        for (int mi = 0; mi < 4; mi++)
            qf[mi] = *(const short8*)(base + (size_t)(mi * 16 + l16) * 1152 + ks * 32 + quad * 8);
        #pragma unroll
        for (int ni = 0; ni < 4; ni++) {
            if (ks == 1 && quad >= 2) kf[ni] = (short8){};
            else kf[ni] = *(const short8*)(base + 384 + (size_t)(ni * 16 + l16) * 1152 + ks * 32 + quad * 8);
        }
        #pragma unroll
        for (int mi = 0; mi < 4; mi++)
            #pragma unroll
            for (int ni = 0; ni < 4; ni++)
                acc[mi][ni] = __builtin_amdgcn_mfma_f32_16x16x32_bf16(qf[mi], kf[ni], acc[mi][ni], 0, 0, 0);
    }

    // softmax in C-layout
    float mx[4][4], sm[4][4];
    #pragma unroll
    for (int mi = 0; mi < 4; mi++)
        #pragma unroll
        for (int r = 0; r < 4; r++) {
            float m = fmaxf(fmaxf(acc[mi][0][r], acc[mi][1][r]), fmaxf(acc[mi][2][r], acc[mi][3][r]));
            mx[mi][r] = m;
        }
    #pragma unroll
    for (int mask = 1; mask < 16; mask <<= 1)
        #pragma unroll
        for (int mi = 0; mi < 4; mi++)
            #pragma unroll
            for (int r = 0; r < 4; r++)
                mx[mi][r] = fmaxf(mx[mi][r], __shfl_xor(mx[mi][r], mask));
    #pragma unroll
    for (int mi = 0; mi < 4; mi++)
        #pragma unroll
        for (int r = 0; r < 4; r++) {
            float s = 0.f;
            #pragma unroll
            for (int ni = 0; ni < 4; ni++) {
                float p = __expf(acc[mi][ni][r] - mx[mi][r]);
                acc[mi][ni][r] = p;
                s += p;
            }
            sm[mi][r] = s;
        }
    #pragma unroll
    for (int mask = 1; mask < 16; mask <<= 1)
        #pragma unroll
        for (int mi = 0; mi < 4; mi++)
            #pragma unroll
            for (int r = 0; r < 4; r++)
                sm[mi][r] += __shfl_xor(sm[mi][r], mask);

    // P (pre-scaled by 1/rowsum) -> LDS (C->A layout transform)
    #pragma unroll
    for (int mi = 0; mi < 4; mi++)
        #pragma unroll
        for (int r = 0; r < 4; r++) {
            float inv = 1.f / sm[mi][r];
            int row = mi * 16 + quad * 4 + r;
            #pragma unroll
            for (int ni = 0; ni < 4; ni++)
                Pl[wv][row * 72 + ni * 16 + l16] = f2b(acc[mi][ni][r] * inv);
        }

    // O = P(64x64) * Vt^T -> (64 x 48)
    floatx4 o[4][3] = {};
    #pragma unroll
    for (int ks = 0; ks < 2; ks++) {
        short8 pf[4], vf[3];
        #pragma unroll
        for (int mi = 0; mi < 4; mi++)
            pf[mi] = *(const short8*)&Pl[wv][(mi * 16 + l16) * 72 + ks * 32 + quad * 8];
        #pragma unroll
        for (int ni = 0; ni < 3; ni++)
            vf[ni] = *(const short8*)&Vt[wv][(ni * 16 + l16) * 72 + ks * 32 + quad * 8];
        #pragma unroll
        for (int mi = 0; mi < 4; mi++)
            #pragma unroll
            for (int ni = 0; ni < 3; ni++)
                o[mi][ni] = __builtin_amdgcn_mfma_f32_16x16x32_bf16(pf[mi], vf[ni], o[mi][ni], 0, 0, 0);
    }

    // O (C-layout) -> Pl staging -> coalesced short8 stores (per-wave, no barrier)
    #pragma unroll
    for (int mi = 0; mi < 4; mi++)
        #pragma unroll
        for (int ni = 0; ni < 3; ni++)
            #pragma unroll
            for (int r = 0; r < 4; r++)
                Pl[wv][(mi * 16 + quad * 4 + r) * 72 + ni * 16 + l16] = f2b(o[mi][ni][r]);
    unsigned short* hw = hwin + (size_t)wid * 64 * 384 + head * 48;
    #pragma unroll
    for (int i2 = 0; i2 < 6; i2++) {
        short8 vv = *(const short8*)&Pl[wv][lane * 72 + i2 * 8];
        *(short8*)&hw[(size_t)lane * 384 + i2 * 8] = vv;
    }
}

// ---------------- 128x128 proj GEMM (BK=64, swizzle) + bias + residual -> fp32 ----------------
__launch_bounds__(256)
__global__ void gemm_proj(const unsigned short* __restrict__ A, const unsigned short* __restrict__ Wb,
                          const float* __restrict__ bias, const float* __restrict__ x,
                          float* __restrict__ out) {
    const int K = 384;
    __shared__ __align__(16) unsigned short As[8192], Bs[8192];
    int l = blockIdx.x;
    int xcd = l & 7, li = l >> 3;
    int m0 = (xcd * 64 + li / 3) * 128, n0 = (li % 3) * 128;
    int t = threadIdx.x;
    int lane = t & 63, wv = t >> 6;
    int wm = wv >> 1, wn = wv & 1;
    int quad = lane >> 4, l16 = lane & 15;
    int sr = lane >> 2, sc = (lane & 3) * 8;
    floatx4 acc[4][4] = {};
    for (int k0 = 0; k0 < K; k0 += 64) {
        #pragma unroll
        for (int p = 0; p < 2; p++)
            #pragma unroll
            for (int rh = 0; rh < 2; rh++) {
                const unsigned short* ga = A  + (size_t)(m0 + wv * 32 + rh * 16 + sr) * K + k0 + p * 32 + sc;
                const unsigned short* gb = Wb + (size_t)(n0 + wv * 32 + rh * 16 + sr) * K + k0 + p * 32 + sc;
                gld16(ga, &As[p * 4096 + (wv * 32 + rh * 16) * 32]);
                gld16(gb, &Bs[p * 4096 + (wv * 32 + rh * 16) * 32]);
            }
        __syncthreads();
        #pragma unroll
        for (int p = 0; p < 2; p++) {
            short8 af[4], bf[4];
            #pragma unroll
            for (int mi = 0; mi < 4; mi++)
                af[mi] = *(const short8*)&As[p * 4096 + (wm * 64 + mi * 16 + l16) * 32 + quad * 8];
            #pragma unroll
            for (int ni = 0; ni < 4; ni++)
                bf[ni] = *(const short8*)&Bs[p * 4096 + (wn * 64 + ni * 16 + l16) * 32 + quad * 8];
            #pragma unroll
            for (int mi = 0; mi < 4; mi++)
                #pragma unroll
                for (int ni = 0; ni < 4; ni++)
                    acc[mi][ni] = __builtin_amdgcn_mfma_f32_16x16x32_bf16(af[mi], bf[ni], acc[mi][ni], 0, 0, 0);
        }
        __syncthreads();
    }
    #pragma unroll
    for (int mi = 0; mi < 4; mi++)
        #pragma unroll
        for (int ni = 0; ni < 4; ni++) {
            int gm = m0 + wm * 64 + mi * 16 + quad * 4;   // 4 consecutive tokens = 4 w-pixels
            int gn = n0 + wn * 64 + ni * 16 + l16;        // channel
            float bv = bias[gn];
            int nw = gm >> 6, s = gm & 63;
            int b = nw >> 6, wh = (nw >> 3) & 7, ww = nw & 7;
            int i = s >> 3, jb = s & 7;
            size_t o = (((size_t)b * CC + gn) * HH + wh * 8 + i) * WWD + ww * 8 + jb;
            float4 xv = *(const float4*)(x + o);
            float4 ov;
            ov.x = acc[mi][ni][0] + bv + xv.x;
            ov.y = acc[mi][ni][1] + bv + xv.y;
            ov.z = acc[mi][ni][2] + bv + xv.z;
            ov.w = acc[mi][ni][3] + bv + xv.w;
            *(float4*)(out + o) = ov;
        }
}

// ---------------- launch ----------------
extern "C" void kernel_launch(void* const* d_in, const int* in_sizes, int n_in,
                              void* d_out, int out_size, void* d_ws, size_t ws_size,
                              hipStream_t stream) {
    const float* x     = (const float*)d_in[0];
    const float* gnw   = (const float*)d_in[1];
    const float* gnb   = (const float*)d_in[2];
    const float* wqkv  = (const float*)d_in[3];
    const float* wproj = (const float*)d_in[4];
    const float* bproj = (const float*)d_in[5];
    float* out = (float*)d_out;

    char* ws = (char*)d_ws;
    float* wsf = (float*)ws;
    const size_t OFF_WQ  = 8192;
    const size_t OFF_WP  = OFF_WQ + (size_t)1152 * 384 * 2;
    const size_t OFF_WIN = 2097152;
    const size_t OFF_QKV = OFF_WIN + (size_t)MTOK * CC * 2 + 2048;
    unsigned short* wq_b = (unsigned short*)(ws + OFF_WQ);
    unsigned short* wp_b = (unsigned short*)(ws + OFF_WP);
    unsigned short* win  = (unsigned short*)(ws + OFF_WIN);
    unsigned short* qkvb = (unsigned short*)(ws + OFF_QKV);
    unsigned short* hwin = win;   // win dead after gemm_qkv; reuse for attention output

    gn_partial<<<512, 256, 0, stream>>>(x, wsf);
    conv_w<<<2304, 256, 0, stream>>>(wqkv, wproj, wq_b, wp_b);
    gn_final<<<1, 64, 0, stream>>>(wsf);
    norm_window<<<1024, 256, 0, stream>>>(x, gnw, gnb, wsf, win);
    gemm_qkv<<<4608, 256, 0, stream>>>(win, wq_b, qkvb);
    attn<<<2048, 256, 0, stream>>>(qkvb, hwin);
    gemm_proj<<<1536, 256, 0, stream>>>(hwin, wp_b, bproj, x, out);
}